// Round 1
// baseline (1527.070 us; speedup 1.0000x reference)
//
#include <hip/hip_runtime.h>
#include <cstdint>
#include <cstddef>

#define S_LEN 512
#define DMODEL 2048
#define NH 16
#define NKVH 4
#define DHEAD 128
#define FFD 2048
#define NEXP 8

typedef __attribute__((ext_vector_type(8))) short s8v;   // 8 bf16 (guide: verified frag type)
typedef __attribute__((ext_vector_type(4))) float f4v;   // 4 fp32 acc

__device__ __forceinline__ unsigned short f2bf(float f) {
    unsigned int u = __float_as_uint(f);
    unsigned int r = u + 0x7fffu + ((u >> 16) & 1u);   // round-to-nearest-even
    return (unsigned short)(r >> 16);
}
__device__ __forceinline__ float bf2f(unsigned short h) {
    return __uint_as_float(((unsigned int)h) << 16);
}

__device__ __forceinline__ f4v mfma_bf16(s8v a, s8v b, f4v c) {
    return __builtin_amdgcn_mfma_f32_16x16x32_bf16(a, b, c, 0, 0, 0);
}

// ---------------------------------------------------------------------------
// RMSNorm producing split bf16 (hi+lo) for high-precision GEMM A operand
// ---------------------------------------------------------------------------
__global__ __launch_bounds__(256) void rms_pair_k(const float* __restrict__ x,
                                                  const float* __restrict__ w,
                                                  unsigned short* __restrict__ hi,
                                                  unsigned short* __restrict__ lo) {
    int row = blockIdx.x;
    const float* xr = x + (size_t)row * DMODEL;
    float ss = 0.f;
    for (int i = threadIdx.x; i < DMODEL; i += 256) { float v = xr[i]; ss = fmaf(v, v, ss); }
    for (int off = 32; off > 0; off >>= 1) ss += __shfl_xor(ss, off);
    __shared__ float red[4];
    if ((threadIdx.x & 63) == 0) red[threadIdx.x >> 6] = ss;
    __syncthreads();
    float tot = (red[0] + red[1]) + (red[2] + red[3]);
    float scale = 1.0f / sqrtf(tot * (1.0f / DMODEL) + 1e-5f);
    for (int i = threadIdx.x; i < DMODEL; i += 256) {
        float v = xr[i] * scale * w[i];
        unsigned short hb = f2bf(v);
        hi[(size_t)row * DMODEL + i] = hb;
        lo[(size_t)row * DMODEL + i] = f2bf(v - bf2f(hb));
    }
}

// RMSNorm producing fp32 (for router) + plain bf16 (for MoE GEMMs)
__global__ __launch_bounds__(256) void rms_dual_k(const float* __restrict__ x,
                                                  const float* __restrict__ w,
                                                  float* __restrict__ xf,
                                                  unsigned short* __restrict__ xb) {
    int row = blockIdx.x;
    const float* xr = x + (size_t)row * DMODEL;
    float ss = 0.f;
    for (int i = threadIdx.x; i < DMODEL; i += 256) { float v = xr[i]; ss = fmaf(v, v, ss); }
    for (int off = 32; off > 0; off >>= 1) ss += __shfl_xor(ss, off);
    __shared__ float red[4];
    if ((threadIdx.x & 63) == 0) red[threadIdx.x >> 6] = ss;
    __syncthreads();
    float tot = (red[0] + red[1]) + (red[2] + red[3]);
    float scale = 1.0f / sqrtf(tot * (1.0f / DMODEL) + 1e-5f);
    for (int i = threadIdx.x; i < DMODEL; i += 256) {
        float v = xr[i] * scale * w[i];
        xf[(size_t)row * DMODEL + i] = v;
        xb[(size_t)row * DMODEL + i] = f2bf(v);
    }
}

// ---------------------------------------------------------------------------
// Generic MFMA GEMM: C[M x N] = A(bf16, [M x 2048]) @ B(fp32, [2048 x N])
//   SPLIT: A given as hi+lo bf16 pair; B split into hi+lo during staging;
//          acc = Ah*Bh + Ah*Bl + Al*Bh  (~fp32 accuracy)
//   gather mode (lists != null): rows of A/C are lists[z][i], M = counts[z],
//          B = Bw + z*bstride  (per-expert weights)
//   epi: 0 = store, 1 = store acc + R, 2 = C += acc
// Tile: BM=64 BN=64 BK=32, 256 threads, 4 waves each 32x32 via 16x16x32 MFMA.
// ---------------------------------------------------------------------------
template <bool SPLIT>
__global__ __launch_bounds__(256) void gemm_k(const unsigned short* __restrict__ Ahi,
                                              const unsigned short* __restrict__ Alo,
                                              const float* __restrict__ Bw,
                                              float* __restrict__ Cc,
                                              const float* __restrict__ Rr,
                                              int M, int N, int epi,
                                              const int* __restrict__ lists,
                                              const int* __restrict__ counts,
                                              long long bstride) {
    __shared__ unsigned short Ah[64][40];                 // [m][k], +8 pad
    __shared__ unsigned short Al[SPLIT ? 64 : 1][40];
    __shared__ unsigned short Bt[64][40];                 // B^T: [n][k]
    __shared__ unsigned short Bl[SPLIT ? 64 : 1][40];

    const int z = blockIdx.z;
    int myM = M;
    const int* rl = nullptr;
    if (lists) { rl = lists + z * S_LEN; myM = counts[z]; }
    const int m0 = blockIdx.y * 64;
    if (m0 >= myM) return;
    const float* Bp = Bw + (long long)z * bstride;
    const int n0 = blockIdx.x * 64;

    const int tid = threadIdx.x;
    const int ar = tid >> 2;            // A stage: row 0..63
    const int ak = (tid & 3) << 3;      //          k 0,8,16,24
    const int bk = tid >> 3;            // B stage: k 0..31
    const int bn = (tid & 7) << 3;      //          n 0..56 step 8

    const int arow = m0 + ar;
    const bool avalid = arow < myM;
    int arow_g = 0;
    if (avalid) arow_g = rl ? rl[arow] : arow;

    const unsigned short* Ahp = Ahi + (size_t)arow_g * DMODEL + ak;
    const unsigned short* Alp = nullptr;
    if constexpr (SPLIT) Alp = Alo + (size_t)arow_g * DMODEL + ak;

    const int lane = tid & 63;
    const int wv = tid >> 6;
    const int wm = wv >> 1;             // wave row 0..1 (32 rows each)
    const int wn = wv & 1;              // wave col 0..1
    const int lr = lane & 15;
    const int quad = lane >> 4;

    f4v zero = {0.f, 0.f, 0.f, 0.f};
    f4v acc[2][2];
    acc[0][0] = zero; acc[0][1] = zero; acc[1][0] = zero; acc[1][1] = zero;

    for (int kt = 0; kt < DMODEL / 32; ++kt) {
        const int k0 = kt << 5;
        // ---- stage A (bf16, 16B per thread per array) ----
        uint4 hv = {0, 0, 0, 0};
        uint4 lv = {0, 0, 0, 0};
        if (avalid) {
            hv = *(const uint4*)(Ahp + k0);
            if constexpr (SPLIT) lv = *(const uint4*)(Alp + k0);
        }
        *(uint4*)&Ah[ar][ak] = hv;
        if constexpr (SPLIT) *(uint4*)&Al[ar][ak] = lv;
        // ---- stage B (fp32 -> bf16 hi/lo, transposed to [n][k]) ----
        const float* brow = Bp + (long long)(k0 + bk) * N + n0 + bn;
        float4 f0 = *(const float4*)(brow);
        float4 f1 = *(const float4*)(brow + 4);
        float bv8[8] = {f0.x, f0.y, f0.z, f0.w, f1.x, f1.y, f1.z, f1.w};
#pragma unroll
        for (int i = 0; i < 8; i++) {
            unsigned short hb = f2bf(bv8[i]);
            Bt[bn + i][bk] = hb;
            if constexpr (SPLIT) Bl[bn + i][bk] = f2bf(bv8[i] - bf2f(hb));
        }
        __syncthreads();
        // ---- fragments + MFMA ----
        s8v ah0 = *(const s8v*)&Ah[wm * 32 + lr][quad * 8];
        s8v ah1 = *(const s8v*)&Ah[wm * 32 + 16 + lr][quad * 8];
        s8v bh0 = *(const s8v*)&Bt[wn * 32 + lr][quad * 8];
        s8v bh1 = *(const s8v*)&Bt[wn * 32 + 16 + lr][quad * 8];
        acc[0][0] = mfma_bf16(ah0, bh0, acc[0][0]);
        acc[0][1] = mfma_bf16(ah0, bh1, acc[0][1]);
        acc[1][0] = mfma_bf16(ah1, bh0, acc[1][0]);
        acc[1][1] = mfma_bf16(ah1, bh1, acc[1][1]);
        if constexpr (SPLIT) {
            s8v al0 = *(const s8v*)&Al[wm * 32 + lr][quad * 8];
            s8v al1 = *(const s8v*)&Al[wm * 32 + 16 + lr][quad * 8];
            s8v bl0 = *(const s8v*)&Bl[wn * 32 + lr][quad * 8];
            s8v bl1 = *(const s8v*)&Bl[wn * 32 + 16 + lr][quad * 8];
            acc[0][0] = mfma_bf16(ah0, bl0, acc[0][0]);
            acc[0][0] = mfma_bf16(al0, bh0, acc[0][0]);
            acc[0][1] = mfma_bf16(ah0, bl1, acc[0][1]);
            acc[0][1] = mfma_bf16(al0, bh1, acc[0][1]);
            acc[1][0] = mfma_bf16(ah1, bl0, acc[1][0]);
            acc[1][0] = mfma_bf16(al1, bh0, acc[1][0]);
            acc[1][1] = mfma_bf16(ah1, bl1, acc[1][1]);
            acc[1][1] = mfma_bf16(al1, bh1, acc[1][1]);
        }
        __syncthreads();
    }
    // ---- epilogue: D[row=(quad*4+r)][col=lane&15] per 16x16 tile ----
#pragma unroll
    for (int t = 0; t < 2; t++) {
#pragma unroll
        for (int u = 0; u < 2; u++) {
#pragma unroll
            for (int r2 = 0; r2 < 4; r2++) {
                int rml = m0 + wm * 32 + t * 16 + quad * 4 + r2;
                if (rml >= myM) continue;
                int rg = rl ? rl[rml] : rml;
                int col = n0 + wn * 32 + u * 16 + lr;
                long long off = (long long)rg * N + col;
                float v = acc[t][u][r2];
                if (epi == 2) Cc[off] += v;
                else if (epi == 1) Cc[off] = v + Rr[off];
                else Cc[off] = v;
            }
        }
    }
}

// ---------------------------------------------------------------------------
// RoPE in place on q [512 x 2048] and k [512 x 512]; pair (i, i+64) per thread
// ---------------------------------------------------------------------------
__global__ __launch_bounds__(256) void rope_k(float* __restrict__ qb, float* __restrict__ kb,
                                              const int* __restrict__ pos_ids) {
    int idx = blockIdx.x * 256 + threadIdx.x;   // S*(NH+NKVH)*64 total
    int i = idx & 63;
    int rest = idx >> 6;
    int head = rest % (NH + NKVH);
    int s = rest / (NH + NKVH);
    if (s >= S_LEN) return;
    float pos = (float)pos_ids[s];
    float inv = (float)exp(-(double)i * (log(500000.0) / 64.0));
    float f = pos * inv;
    float c = cosf(f), sn = sinf(f);
    float* p;
    if (head < NH) p = qb + (size_t)s * (NH * DHEAD) + head * DHEAD;
    else p = kb + (size_t)s * (NKVH * DHEAD) + (head - NH) * DHEAD;
    float x1 = p[i], x2 = p[i + 64];
    p[i] = x1 * c - x2 * sn;
    p[i + 64] = x2 * c + x1 * sn;
}

// ---------------------------------------------------------------------------
// Flash-style causal attention, fp32. Block: 16 q rows of one head; 4 waves,
// 4 q rows each; lane j = key j within the 64-key tile. K and V share LDS.
// Output bf16 hi/lo pair at [s][h*128+d] for the split O-projection.
// ---------------------------------------------------------------------------
__global__ __launch_bounds__(256) void attn_k(const float* __restrict__ qb,
                                              const float* __restrict__ kb,
                                              const float* __restrict__ vb,
                                              const int* __restrict__ amask,
                                              unsigned short* __restrict__ ohi,
                                              unsigned short* __restrict__ olo) {
    __shared__ float KV[64][133];   // pad 133 -> bank (j*5+d)%32, 2-way max
    __shared__ float Qs[16][133];
    __shared__ float Ps[4][4][64];
    const int qt = blockIdx.x;
    const int h = blockIdx.y;
    const int kvh = h >> 2;
    const int tid = threadIdx.x;
    const int w = tid >> 6;
    const int lane = tid & 63;
    const float qsc = 0.08838834764831845f;   // 1/sqrt(128)

    for (int i = tid; i < 16 * 128; i += 256) {
        int r = i >> 7, d = i & 127;
        Qs[r][d] = qb[(size_t)(qt * 16 + r) * (NH * DHEAD) + h * DHEAD + d] * qsc;
    }
    float m_i[4], l_i[4], o0[4], o1[4];
#pragma unroll
    for (int r = 0; r < 4; r++) { m_i[r] = -3.0e38f; l_i[r] = 0.f; o0[r] = 0.f; o1[r] = 0.f; }
    const int ntiles = ((qt * 16 + 15) >> 6) + 1;
    __syncthreads();
    for (int kt = 0; kt < ntiles; kt++) {
        for (int i = tid; i < 64 * 128; i += 256) {
            int r = i >> 7, d = i & 127;
            KV[r][d] = kb[(size_t)(kt * 64 + r) * (NKVH * DHEAD) + kvh * DHEAD + d];
        }
        __syncthreads();
        const int kg = kt * 64 + lane;
        const bool kvalid = (amask[kg] > 0);
        float sc[4] = {0.f, 0.f, 0.f, 0.f};
        for (int d = 0; d < 128; d++) {
            float kval = KV[lane][d];
#pragma unroll
            for (int r = 0; r < 4; r++) sc[r] = fmaf(Qs[w * 4 + r][d], kval, sc[r]);
        }
#pragma unroll
        for (int r = 0; r < 4; r++) {
            const int qg = qt * 16 + w * 4 + r;
            float sr = (kvalid && kg <= qg) ? sc[r] : -1.0e30f;
            float mt = sr;
            for (int off = 32; off > 0; off >>= 1) mt = fmaxf(mt, __shfl_xor(mt, off));
            float mn = fmaxf(m_i[r], mt);
            float p = expf(sr - mn);          // masked & fully-masked tiles -> exact 0
            float alpha = expf(m_i[r] - mn);
            float psum = p;
            for (int off = 32; off > 0; off >>= 1) psum += __shfl_xor(psum, off);
            l_i[r] = l_i[r] * alpha + psum;
            m_i[r] = mn;
            o0[r] *= alpha; o1[r] *= alpha;
            Ps[w][r][lane] = p;
        }
        __syncthreads();
        for (int i = tid; i < 64 * 128; i += 256) {
            int r = i >> 7, d = i & 127;
            KV[r][d] = vb[(size_t)(kt * 64 + r) * (NKVH * DHEAD) + kvh * DHEAD + d];
        }
        __syncthreads();
#pragma unroll 4
        for (int j = 0; j < 64; j++) {
            float v0 = KV[j][lane];
            float v1 = KV[j][lane + 64];
#pragma unroll
            for (int r = 0; r < 4; r++) {
                float p = Ps[w][r][j];
                o0[r] = fmaf(p, v0, o0[r]);
                o1[r] = fmaf(p, v1, o1[r]);
            }
        }
        __syncthreads();
    }
#pragma unroll
    for (int r = 0; r < 4; r++) {
        const int qg = qt * 16 + w * 4 + r;
        float linv = 1.0f / l_i[r];
        float a0 = o0[r] * linv, a1 = o1[r] * linv;
        size_t base = (size_t)qg * (NH * DHEAD) + h * DHEAD;
        unsigned short h0 = f2bf(a0), h1 = f2bf(a1);
        ohi[base + lane] = h0;
        ohi[base + lane + 64] = h1;
        olo[base + lane] = f2bf(a0 - bf2f(h0));
        olo[base + lane + 64] = f2bf(a1 - bf2f(h1));
    }
}

// ---------------------------------------------------------------------------
// Router: logits[t][e] = x2f[t] . rw[:,e]  (fp32 — argmax must match fp32 ref)
// block = one token; 8 groups of 32 lanes, one expert each
// ---------------------------------------------------------------------------
__global__ __launch_bounds__(256) void router_k(const float* __restrict__ x2f,
                                                const float* __restrict__ rw,
                                                float* __restrict__ logits) {
    int t = blockIdx.x;
    int e = threadIdx.x >> 5;
    int j = threadIdx.x & 31;
    const float* xr = x2f + (size_t)t * DMODEL;
    float p = 0.f;
    for (int k = j; k < DMODEL; k += 32) p = fmaf(xr[k], rw[(size_t)k * NEXP + e], p);
    for (int off = 16; off > 0; off >>= 1) p += __shfl_xor(p, off);
    if (j == 0) logits[t * NEXP + e] = p;
}

__global__ __launch_bounds__(512) void route_build_k(const float* __restrict__ logits,
                                                     float* __restrict__ tscore,
                                                     int* __restrict__ counts,
                                                     int* __restrict__ lists) {
    int t = threadIdx.x;
    const float* lg = logits + t * NEXP;
    int best = 0;
    float bv = lg[0];
#pragma unroll
    for (int e = 1; e < NEXP; e++) { float v = lg[e]; if (v > bv) { bv = v; best = e; } }
    tscore[t] = 1.0f / (1.0f + expf(-bv));
    int pos = atomicAdd(&counts[best], 1);
    lists[best * S_LEN + pos] = t;
}

// ---------------------------------------------------------------------------
// silu(g)*u epilogues -> bf16 for the down GEMM A operand
// ---------------------------------------------------------------------------
__global__ __launch_bounds__(256) void silu_shared_k(const float* __restrict__ G,
                                                     const float* __restrict__ U,
                                                     unsigned short* __restrict__ o) {
    int i = blockIdx.x * 256 + threadIdx.x;
    float g = G[i], u = U[i];
    o[i] = f2bf(g / (1.0f + expf(-g)) * u);
}

__global__ __launch_bounds__(256) void silu_routed_k(const float* __restrict__ G,
                                                     const float* __restrict__ U,
                                                     const float* __restrict__ tscore,
                                                     unsigned short* __restrict__ o) {
    int i = blockIdx.x * 256 + threadIdx.x;
    int t = i >> 11;                    // /FFD
    float s = tscore[t];
    float g = s * G[i], u = s * U[i];   // score scales expert INPUT (pre-silu)
    o[i] = f2bf(g / (1.0f + expf(-g)) * u);
}

// ---------------------------------------------------------------------------
extern "C" void kernel_launch(void* const* d_in, const int* in_sizes, int n_in,
                              void* d_out, int out_size, void* d_ws, size_t ws_size,
                              hipStream_t stream) {
    const float* hidden = (const float*)d_in[0];
    const int* amask = (const int*)d_in[1];
    const int* posid = (const int*)d_in[2];
    const float* anw = (const float*)d_in[3];
    const float* wq = (const float*)d_in[4];
    const float* wk = (const float*)d_in[5];
    const float* wvv = (const float*)d_in[6];
    const float* wo = (const float*)d_in[7];
    const float* fnw = (const float*)d_in[8];
    const float* rw = (const float*)d_in[9];
    const float* wg = (const float*)d_in[10];
    const float* wu = (const float*)d_in[11];
    const float* wd = (const float*)d_in[12];
    const float* wsg = (const float*)d_in[13];
    const float* wsu = (const float*)d_in[14];
    const float* wsd = (const float*)d_in[15];
    float* out = (float*)d_out;

    char* ws = (char*)d_ws;
    size_t off = 0;
    auto alloc = [&](size_t bytes) -> void* {
        void* p = ws + off;
        off += (bytes + 255) & ~(size_t)255;
        return p;
    };
    unsigned short* x1h = (unsigned short*)alloc((size_t)S_LEN * DMODEL * 2);
    unsigned short* x1l = (unsigned short*)alloc((size_t)S_LEN * DMODEL * 2);
    float* qb = (float*)alloc((size_t)S_LEN * NH * DHEAD * 4);
    float* kb = (float*)alloc((size_t)S_LEN * NKVH * DHEAD * 4);
    float* vb = (float*)alloc((size_t)S_LEN * NKVH * DHEAD * 4);
    unsigned short* ath = (unsigned short*)alloc((size_t)S_LEN * DMODEL * 2);
    unsigned short* atl = (unsigned short*)alloc((size_t)S_LEN * DMODEL * 2);
    float* hbuf = (float*)alloc((size_t)S_LEN * DMODEL * 4);
    float* x2f = (float*)alloc((size_t)S_LEN * DMODEL * 4);
    unsigned short* x2b = (unsigned short*)alloc((size_t)S_LEN * DMODEL * 2);
    float* Gb = (float*)alloc((size_t)S_LEN * FFD * 4);
    float* Ub = (float*)alloc((size_t)S_LEN * FFD * 4);
    unsigned short* smid = (unsigned short*)alloc((size_t)S_LEN * FFD * 2);
    unsigned short* hmid = (unsigned short*)alloc((size_t)S_LEN * FFD * 2);
    float* logits = (float*)alloc((size_t)S_LEN * NEXP * 4);
    float* tscore = (float*)alloc((size_t)S_LEN * 4);
    int* counts = (int*)alloc(NEXP * 4);
    int* lists = (int*)alloc((size_t)NEXP * S_LEN * 4);

    const long long EXP_STRIDE = (long long)DMODEL * FFD;

    hipMemsetAsync(counts, 0, NEXP * 4, stream);

    // ---- attention block (split-precision GEMMs) ----
    rms_pair_k<<<S_LEN, 256, 0, stream>>>(hidden, anw, x1h, x1l);
    gemm_k<true><<<dim3(32, 8), 256, 0, stream>>>(x1h, x1l, wq, qb, nullptr, S_LEN, 2048, 0, nullptr, nullptr, 0);
    gemm_k<true><<<dim3(8, 8), 256, 0, stream>>>(x1h, x1l, wk, kb, nullptr, S_LEN, 512, 0, nullptr, nullptr, 0);
    gemm_k<true><<<dim3(8, 8), 256, 0, stream>>>(x1h, x1l, wvv, vb, nullptr, S_LEN, 512, 0, nullptr, nullptr, 0);
    rope_k<<<2560, 256, 0, stream>>>(qb, kb, posid);
    attn_k<<<dim3(32, NH), 256, 0, stream>>>(qb, kb, vb, amask, ath, atl);
    gemm_k<true><<<dim3(32, 8), 256, 0, stream>>>(ath, atl, wo, hbuf, hidden, S_LEN, 2048, 1, nullptr, nullptr, 0);

    // ---- MoE block ----
    rms_dual_k<<<S_LEN, 256, 0, stream>>>(hbuf, fnw, x2f, x2b);
    router_k<<<S_LEN, 256, 0, stream>>>(x2f, rw, logits);
    route_build_k<<<1, 512, 0, stream>>>(logits, tscore, counts, lists);

    // shared expert: out = h + (silu(x2@wsg) * (x2@wsu)) @ wsd
    gemm_k<false><<<dim3(32, 8), 256, 0, stream>>>(x2b, nullptr, wsg, Gb, nullptr, S_LEN, FFD, 0, nullptr, nullptr, 0);
    gemm_k<false><<<dim3(32, 8), 256, 0, stream>>>(x2b, nullptr, wsu, Ub, nullptr, S_LEN, FFD, 0, nullptr, nullptr, 0);
    silu_shared_k<<<(S_LEN * FFD) / 256, 256, 0, stream>>>(Gb, Ub, smid);
    gemm_k<false><<<dim3(32, 8), 256, 0, stream>>>(smid, nullptr, wsd, out, hbuf, S_LEN, DMODEL, 1, nullptr, nullptr, 0);

    // routed experts (top-1): gathered GEMMs per expert, scatter rows by token
    gemm_k<false><<<dim3(32, 8, NEXP), 256, 0, stream>>>(x2b, nullptr, wg, Gb, nullptr, S_LEN, FFD, 0, lists, counts, EXP_STRIDE);
    gemm_k<false><<<dim3(32, 8, NEXP), 256, 0, stream>>>(x2b, nullptr, wu, Ub, nullptr, S_LEN, FFD, 0, lists, counts, EXP_STRIDE);
    silu_routed_k<<<(S_LEN * FFD) / 256, 256, 0, stream>>>(Gb, Ub, tscore, hmid);
    gemm_k<false><<<dim3(32, 8, NEXP), 256, 0, stream>>>(hmid, nullptr, wd, out, nullptr, S_LEN, DMODEL, 2, lists, counts, EXP_STRIDE);
}

// Round 2
// 819.360 us; speedup vs baseline: 1.8637x; 1.8637x over previous
//
#include <hip/hip_runtime.h>
#include <cstdint>
#include <cstddef>

#define S_LEN 512
#define DMODEL 2048
#define NH 16
#define NKVH 4
#define DHEAD 128
#define FFD 2048
#define NEXP 8

typedef __attribute__((ext_vector_type(8))) short s8v;   // 8 bf16 (4 VGPRs)
typedef __attribute__((ext_vector_type(4))) float f4v;   // 4 fp32 acc

__device__ __forceinline__ unsigned short f2bf(float f) {
    unsigned int u = __float_as_uint(f);
    unsigned int r = u + 0x7fffu + ((u >> 16) & 1u);   // round-to-nearest-even
    return (unsigned short)(r >> 16);
}
__device__ __forceinline__ float bf2f(unsigned short h) {
    return __uint_as_float(((unsigned int)h) << 16);
}

__device__ __forceinline__ f4v mfma_bf16(s8v a, s8v b, f4v c) {
    return __builtin_amdgcn_mfma_f32_16x16x32_bf16(a, b, c, 0, 0, 0);
}

// ---------------------------------------------------------------------------
// RMSNorm producing split bf16 (hi+lo) for high-precision GEMM A operand
// ---------------------------------------------------------------------------
__global__ __launch_bounds__(256) void rms_pair_k(const float* __restrict__ x,
                                                  const float* __restrict__ w,
                                                  unsigned short* __restrict__ hi,
                                                  unsigned short* __restrict__ lo) {
    int row = blockIdx.x;
    const float* xr = x + (size_t)row * DMODEL;
    float ss = 0.f;
    for (int i = threadIdx.x; i < DMODEL; i += 256) { float v = xr[i]; ss = fmaf(v, v, ss); }
    for (int off = 32; off > 0; off >>= 1) ss += __shfl_xor(ss, off);
    __shared__ float red[4];
    if ((threadIdx.x & 63) == 0) red[threadIdx.x >> 6] = ss;
    __syncthreads();
    float tot = (red[0] + red[1]) + (red[2] + red[3]);
    float scale = 1.0f / sqrtf(tot * (1.0f / DMODEL) + 1e-5f);
    for (int i = threadIdx.x; i < DMODEL; i += 256) {
        float v = xr[i] * scale * w[i];
        unsigned short hb = f2bf(v);
        hi[(size_t)row * DMODEL + i] = hb;
        lo[(size_t)row * DMODEL + i] = f2bf(v - bf2f(hb));
    }
}

// RMSNorm producing fp32 (for router) + plain bf16 (for MoE GEMMs)
__global__ __launch_bounds__(256) void rms_dual_k(const float* __restrict__ x,
                                                  const float* __restrict__ w,
                                                  float* __restrict__ xf,
                                                  unsigned short* __restrict__ xb) {
    int row = blockIdx.x;
    const float* xr = x + (size_t)row * DMODEL;
    float ss = 0.f;
    for (int i = threadIdx.x; i < DMODEL; i += 256) { float v = xr[i]; ss = fmaf(v, v, ss); }
    for (int off = 32; off > 0; off >>= 1) ss += __shfl_xor(ss, off);
    __shared__ float red[4];
    if ((threadIdx.x & 63) == 0) red[threadIdx.x >> 6] = ss;
    __syncthreads();
    float tot = (red[0] + red[1]) + (red[2] + red[3]);
    float scale = 1.0f / sqrtf(tot * (1.0f / DMODEL) + 1e-5f);
    for (int i = threadIdx.x; i < DMODEL; i += 256) {
        float v = xr[i] * scale * w[i];
        xf[(size_t)row * DMODEL + i] = v;
        xb[(size_t)row * DMODEL + i] = f2bf(v);
    }
}

// ---------------------------------------------------------------------------
// K-split MFMA GEMM: C += A(bf16,[M x 2048]) @ B(fp32,[2048 x N]) per k-slice.
//   Always atomicAdd epilogue; C must be pre-initialized (zero or residual).
//   SPLIT: A hi+lo, B split during staging: acc = Ah*Bh + Ah*Bl + Al*Bh.
//   Dual-B (B1 != null): blockIdx.z selects (B0->C0) or (B1->C1).
//   Expert mode (nE>1): blockIdx.z carries expert e; rows gathered via lists.
//   blockIdx.z layout: z = e + nE*( which + ndual*ks )
// Tile: BM=64 BN=64 BK=32, 256 threads, 4 waves each 32x32 via 16x16x32 MFMA.
// B staged k-contiguous per thread (one ds_write_b128, XOR chunk swizzle).
// ---------------------------------------------------------------------------
template <bool SPLIT>
__global__ __launch_bounds__(256) void gemm2_k(const unsigned short* __restrict__ Ahi,
                                               const unsigned short* __restrict__ Alo,
                                               const float* __restrict__ B0,
                                               const float* __restrict__ B1,
                                               float* __restrict__ C0,
                                               float* __restrict__ C1,
                                               int M, int N, int nE, int KS,
                                               const int* __restrict__ lists,
                                               const int* __restrict__ counts,
                                               long long bstride) {
    __shared__ unsigned short Ah[64][40];
    __shared__ unsigned short Al[SPLIT ? 64 : 1][40];
    __shared__ unsigned short Bt[64][40];                 // B^T: [n][k], chunk-swizzled
    __shared__ unsigned short Bl[SPLIT ? 64 : 1][40];

    int z = blockIdx.z;
    int e = 0;
    if (nE > 1) { e = z % nE; z /= nE; }
    int which = 0;
    if (B1 != nullptr) { which = z & 1; z >>= 1; }
    const int ks = z;

    int myM = M;
    const int* rl = nullptr;
    if (lists) { rl = lists + e * S_LEN; myM = counts[e]; }
    const int m0 = blockIdx.y * 64;
    if (m0 >= myM) return;

    const float* Bp = (which ? B1 : B0) + (long long)e * bstride;
    float* Cp = which ? C1 : C0;
    const int n0 = blockIdx.x * 64;

    const int tid = threadIdx.x;
    const int ar = tid >> 2;            // A stage: row 0..63
    const int ak = (tid & 3) << 3;      //          k 0,8,16,24
    const int bn = tid & 63;            // B stage: col 0..63
    const int bk8 = (tid >> 6) << 3;    //          k chunk 0,8,16,24
    const int bc = ((bk8 >> 3) ^ (bn >> 3)) & 3;   // swizzled chunk slot

    const int arow = m0 + ar;
    const bool avalid = arow < myM;
    const int arow_g = avalid ? (rl ? rl[arow] : arow) : 0;

    const unsigned short* Ahp = Ahi + (size_t)arow_g * DMODEL + ak;
    const unsigned short* Alp = SPLIT ? (Alo + (size_t)arow_g * DMODEL + ak) : nullptr;

    const int lane = tid & 63;
    const int wv = tid >> 6;
    const int wm = wv >> 1;             // wave row 0..1
    const int wn = wv & 1;              // wave col 0..1
    const int lr = lane & 15;
    const int quad = lane >> 4;

    f4v zero = {0.f, 0.f, 0.f, 0.f};
    f4v acc[2][2];
    acc[0][0] = zero; acc[0][1] = zero; acc[1][0] = zero; acc[1][1] = zero;

    const int kslice = DMODEL / KS;
    const int kbeg = ks * kslice;
    const int niter = kslice >> 5;

    for (int it = 0; it < niter; ++it) {
        const int k0 = kbeg + (it << 5);
        // ---- global loads first (overlap with other waves' compute) ----
        uint4 hv = {0, 0, 0, 0};
        uint4 lv = {0, 0, 0, 0};
        if (avalid) {
            hv = *(const uint4*)(Ahp + k0);
            if constexpr (SPLIT) lv = *(const uint4*)(Alp + k0);
        }
        const float* bp = Bp + (size_t)(k0 + bk8) * N + n0 + bn;
        float f[8];
#pragma unroll
        for (int j = 0; j < 8; j++) f[j] = bp[(size_t)j * N];
        // pack bf16 hi (and lo)
        unsigned int ph[4], pl[4];
#pragma unroll
        for (int j = 0; j < 4; j++) {
            unsigned short h0 = f2bf(f[2 * j]), h1 = f2bf(f[2 * j + 1]);
            ph[j] = (unsigned int)h0 | ((unsigned int)h1 << 16);
            if constexpr (SPLIT) {
                unsigned short l0 = f2bf(f[2 * j] - bf2f(h0));
                unsigned short l1 = f2bf(f[2 * j + 1] - bf2f(h1));
                pl[j] = (unsigned int)l0 | ((unsigned int)l1 << 16);
            }
        }
        __syncthreads();   // prior iteration's LDS reads complete
        *(uint4*)&Ah[ar][ak] = hv;
        if constexpr (SPLIT) *(uint4*)&Al[ar][ak] = lv;
        *(uint4*)&Bt[bn][bc << 3] = *(uint4*)ph;
        if constexpr (SPLIT) *(uint4*)&Bl[bn][bc << 3] = *(uint4*)pl;
        __syncthreads();
        // ---- fragments + MFMA (B chunk de-swizzled per row) ----
        const int br0 = wn * 32 + lr, br1 = wn * 32 + 16 + lr;
        const int c0 = ((quad ^ (br0 >> 3)) & 3) << 3;
        const int c1 = ((quad ^ (br1 >> 3)) & 3) << 3;
        s8v ah0 = *(const s8v*)&Ah[wm * 32 + lr][quad * 8];
        s8v ah1 = *(const s8v*)&Ah[wm * 32 + 16 + lr][quad * 8];
        s8v bh0 = *(const s8v*)&Bt[br0][c0];
        s8v bh1 = *(const s8v*)&Bt[br1][c1];
        acc[0][0] = mfma_bf16(ah0, bh0, acc[0][0]);
        acc[0][1] = mfma_bf16(ah0, bh1, acc[0][1]);
        acc[1][0] = mfma_bf16(ah1, bh0, acc[1][0]);
        acc[1][1] = mfma_bf16(ah1, bh1, acc[1][1]);
        if constexpr (SPLIT) {
            s8v al0 = *(const s8v*)&Al[wm * 32 + lr][quad * 8];
            s8v al1 = *(const s8v*)&Al[wm * 32 + 16 + lr][quad * 8];
            s8v bl0 = *(const s8v*)&Bl[br0][c0];
            s8v bl1 = *(const s8v*)&Bl[br1][c1];
            acc[0][0] = mfma_bf16(ah0, bl0, acc[0][0]);
            acc[0][0] = mfma_bf16(al0, bh0, acc[0][0]);
            acc[0][1] = mfma_bf16(ah0, bl1, acc[0][1]);
            acc[0][1] = mfma_bf16(al0, bh1, acc[0][1]);
            acc[1][0] = mfma_bf16(ah1, bl0, acc[1][0]);
            acc[1][0] = mfma_bf16(al1, bh0, acc[1][0]);
            acc[1][1] = mfma_bf16(ah1, bl1, acc[1][1]);
            acc[1][1] = mfma_bf16(al1, bh1, acc[1][1]);
        }
    }
    // ---- epilogue: atomic accumulate; D[row=(quad*4+r)][col=lane&15] ----
#pragma unroll
    for (int t = 0; t < 2; t++) {
#pragma unroll
        for (int u = 0; u < 2; u++) {
#pragma unroll
            for (int r2 = 0; r2 < 4; r2++) {
                int rml = m0 + wm * 32 + t * 16 + quad * 4 + r2;
                if (rml >= myM) continue;
                int rg = rl ? rl[rml] : rml;
                int col = n0 + wn * 32 + u * 16 + lr;
                atomicAdd(&Cp[(size_t)rg * N + col], acc[t][u][r2]);
            }
        }
    }
}

// ---------------------------------------------------------------------------
// RoPE in place on q [512 x 2048] and k [512 x 512]; pair (i, i+64) per thread
// ---------------------------------------------------------------------------
__global__ __launch_bounds__(256) void rope_k(float* __restrict__ qb, float* __restrict__ kb,
                                              const int* __restrict__ pos_ids) {
    int idx = blockIdx.x * 256 + threadIdx.x;   // S*(NH+NKVH)*64 total
    int i = idx & 63;
    int rest = idx >> 6;
    int head = rest % (NH + NKVH);
    int s = rest / (NH + NKVH);
    if (s >= S_LEN) return;
    float pos = (float)pos_ids[s];
    float inv = (float)exp(-(double)i * (log(500000.0) / 64.0));
    float f = pos * inv;
    float c = cosf(f), sn = sinf(f);
    float* p;
    if (head < NH) p = qb + (size_t)s * (NH * DHEAD) + head * DHEAD;
    else p = kb + (size_t)s * (NKVH * DHEAD) + (head - NH) * DHEAD;
    float x1 = p[i], x2 = p[i + 64];
    p[i] = x1 * c - x2 * sn;
    p[i + 64] = x2 * c + x1 * sn;
}

// ---------------------------------------------------------------------------
// Flash-style causal attention, fp32. Block: 16 q rows of one head; 4 waves,
// 4 q rows each; lane j = key j within the 64-key tile. K and V share LDS.
// Output bf16 hi/lo pair at [s][h*128+d] for the split O-projection.
// ---------------------------------------------------------------------------
__global__ __launch_bounds__(256) void attn_k(const float* __restrict__ qb,
                                              const float* __restrict__ kb,
                                              const float* __restrict__ vb,
                                              const int* __restrict__ amask,
                                              unsigned short* __restrict__ ohi,
                                              unsigned short* __restrict__ olo) {
    __shared__ float KV[64][133];
    __shared__ float Qs[16][133];
    __shared__ float Ps[4][4][64];
    const int qt = blockIdx.x;
    const int h = blockIdx.y;
    const int kvh = h >> 2;
    const int tid = threadIdx.x;
    const int w = tid >> 6;
    const int lane = tid & 63;
    const float qsc = 0.08838834764831845f;   // 1/sqrt(128)

    for (int i = tid; i < 16 * 128; i += 256) {
        int r = i >> 7, d = i & 127;
        Qs[r][d] = qb[(size_t)(qt * 16 + r) * (NH * DHEAD) + h * DHEAD + d] * qsc;
    }
    float m_i[4], l_i[4], o0[4], o1[4];
#pragma unroll
    for (int r = 0; r < 4; r++) { m_i[r] = -3.0e38f; l_i[r] = 0.f; o0[r] = 0.f; o1[r] = 0.f; }
    const int ntiles = ((qt * 16 + 15) >> 6) + 1;
    __syncthreads();
    for (int kt = 0; kt < ntiles; kt++) {
        for (int i = tid; i < 64 * 128; i += 256) {
            int r = i >> 7, d = i & 127;
            KV[r][d] = kb[(size_t)(kt * 64 + r) * (NKVH * DHEAD) + kvh * DHEAD + d];
        }
        __syncthreads();
        const int kg = kt * 64 + lane;
        const bool kvalid = (amask[kg] > 0);
        float sc[4] = {0.f, 0.f, 0.f, 0.f};
        for (int d = 0; d < 128; d++) {
            float kval = KV[lane][d];
#pragma unroll
            for (int r = 0; r < 4; r++) sc[r] = fmaf(Qs[w * 4 + r][d], kval, sc[r]);
        }
#pragma unroll
        for (int r = 0; r < 4; r++) {
            const int qg = qt * 16 + w * 4 + r;
            float sr = (kvalid && kg <= qg) ? sc[r] : -1.0e30f;
            float mt = sr;
            for (int off = 32; off > 0; off >>= 1) mt = fmaxf(mt, __shfl_xor(mt, off));
            float mn = fmaxf(m_i[r], mt);
            float p = expf(sr - mn);
            float alpha = expf(m_i[r] - mn);
            float psum = p;
            for (int off = 32; off > 0; off >>= 1) psum += __shfl_xor(psum, off);
            l_i[r] = l_i[r] * alpha + psum;
            m_i[r] = mn;
            o0[r] *= alpha; o1[r] *= alpha;
            Ps[w][r][lane] = p;
        }
        __syncthreads();
        for (int i = tid; i < 64 * 128; i += 256) {
            int r = i >> 7, d = i & 127;
            KV[r][d] = vb[(size_t)(kt * 64 + r) * (NKVH * DHEAD) + kvh * DHEAD + d];
        }
        __syncthreads();
#pragma unroll 4
        for (int j = 0; j < 64; j++) {
            float v0 = KV[j][lane];
            float v1 = KV[j][lane + 64];
#pragma unroll
            for (int r = 0; r < 4; r++) {
                float p = Ps[w][r][j];
                o0[r] = fmaf(p, v0, o0[r]);
                o1[r] = fmaf(p, v1, o1[r]);
            }
        }
        __syncthreads();
    }
#pragma unroll
    for (int r = 0; r < 4; r++) {
        const int qg = qt * 16 + w * 4 + r;
        float linv = 1.0f / l_i[r];
        float a0 = o0[r] * linv, a1 = o1[r] * linv;
        size_t base = (size_t)qg * (NH * DHEAD) + h * DHEAD;
        unsigned short h0 = f2bf(a0), h1 = f2bf(a1);
        ohi[base + lane] = h0;
        ohi[base + lane + 64] = h1;
        olo[base + lane] = f2bf(a0 - bf2f(h0));
        olo[base + lane + 64] = f2bf(a1 - bf2f(h1));
    }
}

// ---------------------------------------------------------------------------
// Router: logits[t][e] = x2f[t] . rw[:,e]  (fp32 — argmax must match fp32 ref)
// ---------------------------------------------------------------------------
__global__ __launch_bounds__(256) void router_k(const float* __restrict__ x2f,
                                                const float* __restrict__ rw,
                                                float* __restrict__ logits) {
    int t = blockIdx.x;
    int e = threadIdx.x >> 5;
    int j = threadIdx.x & 31;
    const float* xr = x2f + (size_t)t * DMODEL;
    float p = 0.f;
    for (int k = j; k < DMODEL; k += 32) p = fmaf(xr[k], rw[(size_t)k * NEXP + e], p);
    for (int off = 16; off > 0; off >>= 1) p += __shfl_xor(p, off);
    if (j == 0) logits[t * NEXP + e] = p;
}

__global__ __launch_bounds__(512) void route_build_k(const float* __restrict__ logits,
                                                     float* __restrict__ tscore,
                                                     int* __restrict__ counts,
                                                     int* __restrict__ lists) {
    int t = threadIdx.x;
    const float* lg = logits + t * NEXP;
    int best = 0;
    float bv = lg[0];
#pragma unroll
    for (int e = 1; e < NEXP; e++) { float v = lg[e]; if (v > bv) { bv = v; best = e; } }
    tscore[t] = 1.0f / (1.0f + expf(-bv));
    int pos = atomicAdd(&counts[best], 1);
    lists[best * S_LEN + pos] = t;
}

// ---------------------------------------------------------------------------
// silu(g)*u epilogues -> bf16 for the down GEMM A operand
// ---------------------------------------------------------------------------
__global__ __launch_bounds__(256) void silu_shared_k(const float* __restrict__ G,
                                                     const float* __restrict__ U,
                                                     unsigned short* __restrict__ o) {
    int i = blockIdx.x * 256 + threadIdx.x;
    float g = G[i], u = U[i];
    o[i] = f2bf(g / (1.0f + expf(-g)) * u);
}

__global__ __launch_bounds__(256) void silu_routed_k(const float* __restrict__ G,
                                                     const float* __restrict__ U,
                                                     const float* __restrict__ tscore,
                                                     unsigned short* __restrict__ o) {
    int i = blockIdx.x * 256 + threadIdx.x;
    int t = i >> 11;                    // /FFD
    float s = tscore[t];
    float g = s * G[i], u = s * U[i];   // score scales expert INPUT (pre-silu)
    o[i] = f2bf(g / (1.0f + expf(-g)) * u);
}

// ---------------------------------------------------------------------------
extern "C" void kernel_launch(void* const* d_in, const int* in_sizes, int n_in,
                              void* d_out, int out_size, void* d_ws, size_t ws_size,
                              hipStream_t stream) {
    const float* hidden = (const float*)d_in[0];
    const int* amask = (const int*)d_in[1];
    const int* posid = (const int*)d_in[2];
    const float* anw = (const float*)d_in[3];
    const float* wq = (const float*)d_in[4];
    const float* wk = (const float*)d_in[5];
    const float* wvv = (const float*)d_in[6];
    const float* wo = (const float*)d_in[7];
    const float* fnw = (const float*)d_in[8];
    const float* rw = (const float*)d_in[9];
    const float* wg = (const float*)d_in[10];
    const float* wu = (const float*)d_in[11];
    const float* wd = (const float*)d_in[12];
    const float* wsg = (const float*)d_in[13];
    const float* wsu = (const float*)d_in[14];
    const float* wsd = (const float*)d_in[15];
    float* out = (float*)d_out;

    char* ws = (char*)d_ws;
    size_t off = 0;
    auto alloc = [&](size_t bytes) -> void* {
        void* p = ws + off;
        off += (bytes + 255) & ~(size_t)255;
        return p;
    };
    unsigned short* x1h = (unsigned short*)alloc((size_t)S_LEN * DMODEL * 2);
    unsigned short* x1l = (unsigned short*)alloc((size_t)S_LEN * DMODEL * 2);
    float* qb = (float*)alloc((size_t)S_LEN * NH * DHEAD * 4);
    float* kb = (float*)alloc((size_t)S_LEN * NKVH * DHEAD * 4);
    float* vb = (float*)alloc((size_t)S_LEN * NKVH * DHEAD * 4);
    unsigned short* ath = (unsigned short*)alloc((size_t)S_LEN * DMODEL * 2);
    unsigned short* atl = (unsigned short*)alloc((size_t)S_LEN * DMODEL * 2);
    float* hbuf = (float*)alloc((size_t)S_LEN * DMODEL * 4);
    float* x2f = (float*)alloc((size_t)S_LEN * DMODEL * 4);
    unsigned short* x2b = (unsigned short*)alloc((size_t)S_LEN * DMODEL * 2);
    float* Gb = (float*)alloc((size_t)S_LEN * FFD * 4);
    float* Ub = (float*)alloc((size_t)S_LEN * FFD * 4);
    float* G2 = (float*)alloc((size_t)S_LEN * FFD * 4);
    float* U2 = (float*)alloc((size_t)S_LEN * FFD * 4);
    unsigned short* smid = (unsigned short*)alloc((size_t)S_LEN * FFD * 2);
    unsigned short* hmid = (unsigned short*)alloc((size_t)S_LEN * FFD * 2);
    float* logits = (float*)alloc((size_t)S_LEN * NEXP * 4);
    float* tscore = (float*)alloc((size_t)S_LEN * 4);
    int* counts = (int*)alloc(NEXP * 4);
    int* lists = (int*)alloc((size_t)NEXP * S_LEN * 4);

    const long long EXP_STRIDE = (long long)DMODEL * FFD;

    // ---- zero-init all atomic-accumulated buffers up front ----
    hipMemsetAsync(counts, 0, NEXP * 4, stream);
    hipMemsetAsync(qb, 0, (size_t)S_LEN * NH * DHEAD * 4, stream);
    hipMemsetAsync(kb, 0, (size_t)S_LEN * NKVH * DHEAD * 4, stream);
    hipMemsetAsync(vb, 0, (size_t)S_LEN * NKVH * DHEAD * 4, stream);
    hipMemsetAsync(Gb, 0, (size_t)S_LEN * FFD * 4, stream);
    hipMemsetAsync(Ub, 0, (size_t)S_LEN * FFD * 4, stream);
    hipMemsetAsync(G2, 0, (size_t)S_LEN * FFD * 4, stream);
    hipMemsetAsync(U2, 0, (size_t)S_LEN * FFD * 4, stream);
    // h starts as the residual; wo-GEMM accumulates attn into it
    hipMemcpyAsync(hbuf, hidden, (size_t)S_LEN * DMODEL * 4, hipMemcpyDeviceToDevice, stream);

    // ---- attention block (split-precision GEMMs, K-split 4) ----
    rms_pair_k<<<S_LEN, 256, 0, stream>>>(hidden, anw, x1h, x1l);
    gemm2_k<true><<<dim3(32, 8, 4), 256, 0, stream>>>(x1h, x1l, wq, nullptr, qb, nullptr,
                                                      S_LEN, 2048, 1, 4, nullptr, nullptr, 0);
    gemm2_k<true><<<dim3(8, 8, 8), 256, 0, stream>>>(x1h, x1l, wk, wvv, kb, vb,
                                                     S_LEN, 512, 1, 4, nullptr, nullptr, 0);
    rope_k<<<2560, 256, 0, stream>>>(qb, kb, posid);
    attn_k<<<dim3(32, NH), 256, 0, stream>>>(qb, kb, vb, amask, ath, atl);
    gemm2_k<true><<<dim3(32, 8, 4), 256, 0, stream>>>(ath, atl, wo, nullptr, hbuf, nullptr,
                                                      S_LEN, 2048, 1, 4, nullptr, nullptr, 0);

    // ---- MoE block ----
    rms_dual_k<<<S_LEN, 256, 0, stream>>>(hbuf, fnw, x2f, x2b);
    router_k<<<S_LEN, 256, 0, stream>>>(x2f, rw, logits);
    route_build_k<<<1, 512, 0, stream>>>(logits, tscore, counts, lists);

    // out starts as h; shared-down and routed-down accumulate into it
    hipMemcpyAsync(out, hbuf, (size_t)S_LEN * DMODEL * 4, hipMemcpyDeviceToDevice, stream);

    // shared expert: gate+up fused in one dispatch, then silu, then down -> out
    gemm2_k<false><<<dim3(32, 8, 8), 256, 0, stream>>>(x2b, nullptr, wsg, wsu, Gb, Ub,
                                                       S_LEN, FFD, 1, 4, nullptr, nullptr, 0);
    silu_shared_k<<<(S_LEN * FFD) / 256, 256, 0, stream>>>(Gb, Ub, smid);
    gemm2_k<false><<<dim3(32, 8, 4), 256, 0, stream>>>(smid, nullptr, wsd, nullptr, out, nullptr,
                                                       S_LEN, DMODEL, 1, 4, nullptr, nullptr, 0);

    // routed experts (top-1): gathered gate+up fused, silu, down -> out
    gemm2_k<false><<<dim3(32, 8, 64), 256, 0, stream>>>(x2b, nullptr, wg, wu, G2, U2,
                                                        S_LEN, FFD, NEXP, 4, lists, counts, EXP_STRIDE);
    silu_routed_k<<<(S_LEN * FFD) / 256, 256, 0, stream>>>(G2, U2, tscore, hmid);
    gemm2_k<false><<<dim3(32, 8, 32), 256, 0, stream>>>(hmid, nullptr, wd, nullptr, out, nullptr,
                                                        S_LEN, DMODEL, NEXP, 4, lists, counts, EXP_STRIDE);
}

// Round 3
// 816.004 us; speedup vs baseline: 1.8714x; 1.0041x over previous
//
#include <hip/hip_runtime.h>
#include <cstdint>
#include <cstddef>

#define S_LEN 512
#define DMODEL 2048
#define NH 16
#define NKVH 4
#define DHEAD 128
#define FFD 2048
#define NEXP 8

typedef __attribute__((ext_vector_type(8))) short s8v;   // 8 bf16 (4 VGPRs)
typedef __attribute__((ext_vector_type(4))) float f4v;   // 4 fp32 acc

__device__ __forceinline__ unsigned short f2bf(float f) {
    unsigned int u = __float_as_uint(f);
    unsigned int r = u + 0x7fffu + ((u >> 16) & 1u);   // round-to-nearest-even
    return (unsigned short)(r >> 16);
}
__device__ __forceinline__ float bf2f(unsigned short h) {
    return __uint_as_float(((unsigned int)h) << 16);
}
__device__ __forceinline__ f4v mfma_bf16(s8v a, s8v b, f4v c) {
    return __builtin_amdgcn_mfma_f32_16x16x32_bf16(a, b, c, 0, 0, 0);
}

// ---------------------------------------------------------------------------
// RMSNorm producing split bf16 (hi+lo) for high-precision GEMM A operand
// ---------------------------------------------------------------------------
__global__ __launch_bounds__(256) void rms_pair_k(const float* __restrict__ x,
                                                  const float* __restrict__ w,
                                                  unsigned short* __restrict__ hi,
                                                  unsigned short* __restrict__ lo) {
    int row = blockIdx.x;
    const float* xr = x + (size_t)row * DMODEL;
    float ss = 0.f;
    for (int i = threadIdx.x; i < DMODEL; i += 256) { float v = xr[i]; ss = fmaf(v, v, ss); }
    for (int off = 32; off > 0; off >>= 1) ss += __shfl_xor(ss, off);
    __shared__ float red[4];
    if ((threadIdx.x & 63) == 0) red[threadIdx.x >> 6] = ss;
    __syncthreads();
    float tot = (red[0] + red[1]) + (red[2] + red[3]);
    float scale = 1.0f / sqrtf(tot * (1.0f / DMODEL) + 1e-5f);
    for (int i = threadIdx.x; i < DMODEL; i += 256) {
        float v = xr[i] * scale * w[i];
        unsigned short hb = f2bf(v);
        hi[(size_t)row * DMODEL + i] = hb;
        lo[(size_t)row * DMODEL + i] = f2bf(v - bf2f(hb));
    }
}

// h = hidden + hs0 + hs1 (wo K-split slabs); store hbuf; RMSNorm -> xf fp32 + xb bf16
__global__ __launch_bounds__(256) void rms_dual2_k(const float* __restrict__ hidden,
                                                   const float* __restrict__ hs0,
                                                   const float* __restrict__ hs1,
                                                   const float* __restrict__ w,
                                                   float* __restrict__ hbuf,
                                                   float* __restrict__ xf,
                                                   unsigned short* __restrict__ xb) {
    __shared__ float vrow[DMODEL];
    int row = blockIdx.x;
    size_t base = (size_t)row * DMODEL;
    float ss = 0.f;
    for (int i = threadIdx.x; i < DMODEL; i += 256) {
        float v = hidden[base + i] + hs0[base + i] + hs1[base + i];
        vrow[i] = v;
        hbuf[base + i] = v;
        ss = fmaf(v, v, ss);
    }
    for (int off = 32; off > 0; off >>= 1) ss += __shfl_xor(ss, off);
    __shared__ float red[4];
    if ((threadIdx.x & 63) == 0) red[threadIdx.x >> 6] = ss;
    __syncthreads();
    float tot = (red[0] + red[1]) + (red[2] + red[3]);
    float scale = 1.0f / sqrtf(tot * (1.0f / DMODEL) + 1e-5f);
    for (int i = threadIdx.x; i < DMODEL; i += 256) {
        float v = vrow[i] * scale * w[i];
        xf[base + i] = v;
        xb[base + i] = f2bf(v);
    }
}

// ---------------------------------------------------------------------------
// Split-precision MFMA GEMM, up to 3 weight matrices side-by-side over x,
// K-split 2 with private fp32 slab outputs (plain stores, no atomics).
// C_mat_ks[m][n] = sum_{k in slice ks} A[m][k]*B_mat[k][n], high precision via
// acc = Ah*Bh + Ah*Bl + Al*Bh. A dense [512 x 2048] bf16 hi/lo.
// ---------------------------------------------------------------------------
struct S3Args {
    const unsigned short* Ahi; const unsigned short* Alo;
    const float* B0; const float* B1; const float* B2;
    float* C00; float* C01; float* C10; float* C11; float* C20; float* C21;
    int N0, N1, N2;
    int x1, x2;          // x-tile boundaries: mat0 if x<x1, mat1 if x<x2, else mat2
};

__global__ __launch_bounds__(256) void gemm_split3_k(S3Args a) {
    __shared__ unsigned short Ah[64][40];
    __shared__ unsigned short Al[64][40];
    __shared__ unsigned short Bt[64][40];
    __shared__ unsigned short Bl[64][40];

    const int x = blockIdx.x;
    const float* Bp; float* Cp; int N; int n0;
    if (x < a.x1)      { Bp = a.B0; N = a.N0; n0 = x * 64;
                         Cp = blockIdx.z ? a.C01 : a.C00; }
    else if (x < a.x2) { Bp = a.B1; N = a.N1; n0 = (x - a.x1) * 64;
                         Cp = blockIdx.z ? a.C11 : a.C10; }
    else               { Bp = a.B2; N = a.N2; n0 = (x - a.x2) * 64;
                         Cp = blockIdx.z ? a.C21 : a.C20; }
    const int m0 = blockIdx.y * 64;
    const int kbeg = blockIdx.z * (DMODEL / 2);

    const int tid = threadIdx.x;
    const int ar = tid >> 2, ak = (tid & 3) << 3;
    const int bn = tid & 63, bk8 = (tid >> 6) << 3;
    const int bc = ((bk8 >> 3) ^ (bn >> 3)) & 3;

    const unsigned short* Ahp = a.Ahi + (size_t)(m0 + ar) * DMODEL + ak;
    const unsigned short* Alp = a.Alo + (size_t)(m0 + ar) * DMODEL + ak;

    const int lane = tid & 63, wv = tid >> 6;
    const int wm = wv >> 1, wn = wv & 1;
    const int lr = lane & 15, quad = lane >> 4;

    f4v zero = {0.f, 0.f, 0.f, 0.f};
    f4v acc[2][2];
    acc[0][0] = zero; acc[0][1] = zero; acc[1][0] = zero; acc[1][1] = zero;

    for (int it = 0; it < 32; ++it) {
        const int k0 = kbeg + (it << 5);
        uint4 hv = *(const uint4*)(Ahp + k0);
        uint4 lv = *(const uint4*)(Alp + k0);
        const float* bp = Bp + (size_t)(k0 + bk8) * N + n0 + bn;
        float f[8];
#pragma unroll
        for (int j = 0; j < 8; j++) f[j] = bp[(size_t)j * N];
        unsigned int ph[4], pl[4];
#pragma unroll
        for (int j = 0; j < 4; j++) {
            unsigned short h0 = f2bf(f[2 * j]), h1 = f2bf(f[2 * j + 1]);
            ph[j] = (unsigned int)h0 | ((unsigned int)h1 << 16);
            unsigned short l0 = f2bf(f[2 * j] - bf2f(h0));
            unsigned short l1 = f2bf(f[2 * j + 1] - bf2f(h1));
            pl[j] = (unsigned int)l0 | ((unsigned int)l1 << 16);
        }
        __syncthreads();
        *(uint4*)&Ah[ar][ak] = hv;
        *(uint4*)&Al[ar][ak] = lv;
        *(uint4*)&Bt[bn][bc << 3] = *(uint4*)ph;
        *(uint4*)&Bl[bn][bc << 3] = *(uint4*)pl;
        __syncthreads();
        const int br0 = wn * 32 + lr, br1 = wn * 32 + 16 + lr;
        const int c0 = ((quad ^ (br0 >> 3)) & 3) << 3;
        const int c1 = ((quad ^ (br1 >> 3)) & 3) << 3;
        s8v ah0 = *(const s8v*)&Ah[wm * 32 + lr][quad * 8];
        s8v ah1 = *(const s8v*)&Ah[wm * 32 + 16 + lr][quad * 8];
        s8v bh0 = *(const s8v*)&Bt[br0][c0];
        s8v bh1 = *(const s8v*)&Bt[br1][c1];
        acc[0][0] = mfma_bf16(ah0, bh0, acc[0][0]);
        acc[0][1] = mfma_bf16(ah0, bh1, acc[0][1]);
        acc[1][0] = mfma_bf16(ah1, bh0, acc[1][0]);
        acc[1][1] = mfma_bf16(ah1, bh1, acc[1][1]);
        s8v al0 = *(const s8v*)&Al[wm * 32 + lr][quad * 8];
        s8v al1 = *(const s8v*)&Al[wm * 32 + 16 + lr][quad * 8];
        s8v bl0 = *(const s8v*)&Bl[br0][c0];
        s8v bl1 = *(const s8v*)&Bl[br1][c1];
        acc[0][0] = mfma_bf16(ah0, bl0, acc[0][0]);
        acc[0][0] = mfma_bf16(al0, bh0, acc[0][0]);
        acc[0][1] = mfma_bf16(ah0, bl1, acc[0][1]);
        acc[0][1] = mfma_bf16(al0, bh1, acc[0][1]);
        acc[1][0] = mfma_bf16(ah1, bl0, acc[1][0]);
        acc[1][0] = mfma_bf16(al1, bh0, acc[1][0]);
        acc[1][1] = mfma_bf16(ah1, bl1, acc[1][1]);
        acc[1][1] = mfma_bf16(al1, bh1, acc[1][1]);
    }
#pragma unroll
    for (int t = 0; t < 2; t++)
#pragma unroll
        for (int u = 0; u < 2; u++)
#pragma unroll
            for (int r2 = 0; r2 < 4; r2++) {
                int row = m0 + wm * 32 + t * 16 + quad * 4 + r2;
                int col = n0 + wn * 32 + u * 16 + lr;
                Cp[(size_t)row * N + col] = acc[t][u][r2];
            }
}

// ---------------------------------------------------------------------------
// Fused gate+up GEMM with in-register silu(s*g)*(s*u), bf16 output, full K,
// no atomics. z = 0..7 routed expert (gathered rows, scale=tscore),
// z = 8 shared expert (dense rows, scale=1, output smid).
// ---------------------------------------------------------------------------
__global__ __launch_bounds__(256) void gemm_gu_k(const unsigned short* __restrict__ Ab,
                                                 const float* __restrict__ wg,
                                                 const float* __restrict__ wu,
                                                 const float* __restrict__ wsg,
                                                 const float* __restrict__ wsu,
                                                 const float* __restrict__ tscore,
                                                 const int* __restrict__ lists,
                                                 const int* __restrict__ counts,
                                                 unsigned short* __restrict__ hmid,
                                                 unsigned short* __restrict__ smid) {
    __shared__ unsigned short Ah[64][40];
    __shared__ unsigned short Bg[64][40];
    __shared__ unsigned short Bu[64][40];

    const int e = blockIdx.z;
    const bool routed = e < NEXP;
    const int* rl = routed ? lists + e * S_LEN : nullptr;
    const int myM = routed ? counts[e] : S_LEN;
    const int m0 = blockIdx.y * 64;
    if (m0 >= myM) return;
    const long long ST = (long long)DMODEL * FFD;
    const float* Bgp = routed ? wg + (long long)e * ST : wsg;
    const float* Bup = routed ? wu + (long long)e * ST : wsu;
    unsigned short* outp = routed ? hmid : smid;
    const int n0 = blockIdx.x * 64;

    const int tid = threadIdx.x;
    const int ar = tid >> 2, ak = (tid & 3) << 3;
    const int bn = tid & 63, bk8 = (tid >> 6) << 3;
    const int bc = ((bk8 >> 3) ^ (bn >> 3)) & 3;

    const int arow = m0 + ar;
    const bool avalid = arow < myM;
    const int arow_g = avalid ? (rl ? rl[arow] : arow) : 0;
    const unsigned short* Ap = Ab + (size_t)arow_g * DMODEL + ak;

    const int lane = tid & 63, wv = tid >> 6;
    const int wm = wv >> 1, wn = wv & 1;
    const int lr = lane & 15, quad = lane >> 4;

    f4v zero = {0.f, 0.f, 0.f, 0.f};
    f4v ag[2][2], au[2][2];
#pragma unroll
    for (int t = 0; t < 2; t++)
#pragma unroll
        for (int u = 0; u < 2; u++) { ag[t][u] = zero; au[t][u] = zero; }

    for (int it = 0; it < DMODEL / 32; ++it) {
        const int k0 = it << 5;
        uint4 hv = {0, 0, 0, 0};
        if (avalid) hv = *(const uint4*)(Ap + k0);
        const float* bgp = Bgp + (size_t)(k0 + bk8) * FFD + n0 + bn;
        const float* bup = Bup + (size_t)(k0 + bk8) * FFD + n0 + bn;
        float fg[8], fu[8];
#pragma unroll
        for (int j = 0; j < 8; j++) fg[j] = bgp[(size_t)j * FFD];
#pragma unroll
        for (int j = 0; j < 8; j++) fu[j] = bup[(size_t)j * FFD];
        unsigned int pg[4], pu[4];
#pragma unroll
        for (int j = 0; j < 4; j++) {
            pg[j] = (unsigned int)f2bf(fg[2 * j]) | ((unsigned int)f2bf(fg[2 * j + 1]) << 16);
            pu[j] = (unsigned int)f2bf(fu[2 * j]) | ((unsigned int)f2bf(fu[2 * j + 1]) << 16);
        }
        __syncthreads();
        *(uint4*)&Ah[ar][ak] = hv;
        *(uint4*)&Bg[bn][bc << 3] = *(uint4*)pg;
        *(uint4*)&Bu[bn][bc << 3] = *(uint4*)pu;
        __syncthreads();
        const int br0 = wn * 32 + lr, br1 = wn * 32 + 16 + lr;
        const int c0 = ((quad ^ (br0 >> 3)) & 3) << 3;
        const int c1 = ((quad ^ (br1 >> 3)) & 3) << 3;
        s8v ah0 = *(const s8v*)&Ah[wm * 32 + lr][quad * 8];
        s8v ah1 = *(const s8v*)&Ah[wm * 32 + 16 + lr][quad * 8];
        s8v g0 = *(const s8v*)&Bg[br0][c0];
        s8v g1 = *(const s8v*)&Bg[br1][c1];
        s8v u0 = *(const s8v*)&Bu[br0][c0];
        s8v u1 = *(const s8v*)&Bu[br1][c1];
        ag[0][0] = mfma_bf16(ah0, g0, ag[0][0]);
        ag[0][1] = mfma_bf16(ah0, g1, ag[0][1]);
        ag[1][0] = mfma_bf16(ah1, g0, ag[1][0]);
        ag[1][1] = mfma_bf16(ah1, g1, ag[1][1]);
        au[0][0] = mfma_bf16(ah0, u0, au[0][0]);
        au[0][1] = mfma_bf16(ah0, u1, au[0][1]);
        au[1][0] = mfma_bf16(ah1, u0, au[1][0]);
        au[1][1] = mfma_bf16(ah1, u1, au[1][1]);
    }
#pragma unroll
    for (int t = 0; t < 2; t++)
#pragma unroll
        for (int u = 0; u < 2; u++)
#pragma unroll
            for (int r2 = 0; r2 < 4; r2++) {
                int rml = m0 + wm * 32 + t * 16 + quad * 4 + r2;
                if (rml >= myM) continue;
                int rg = rl ? rl[rml] : rml;
                float s = routed ? tscore[rg] : 1.0f;
                float g = s * ag[t][u][r2];
                float uu = s * au[t][u][r2];
                float val = g / (1.0f + expf(-g)) * uu;
                int col = n0 + wn * 32 + u * 16 + lr;
                outp[(size_t)rg * FFD + col] = f2bf(val);
            }
}

// ---------------------------------------------------------------------------
// Down GEMM (routed + shared combined), K-split 2 into private fp32 slabs.
// z = ks*9 + e; e<8 routed (A=hmid gathered), e==8 shared (A=smid dense).
// ---------------------------------------------------------------------------
__global__ __launch_bounds__(256) void gemm_dn_k(const unsigned short* __restrict__ hmid,
                                                 const unsigned short* __restrict__ smid,
                                                 const float* __restrict__ wd,
                                                 const float* __restrict__ wsd,
                                                 const int* __restrict__ lists,
                                                 const int* __restrict__ counts,
                                                 float* __restrict__ dR0, float* __restrict__ dR1,
                                                 float* __restrict__ dS0, float* __restrict__ dS1) {
    __shared__ unsigned short Ah[64][40];
    __shared__ unsigned short Bt[64][40];

    const int e = blockIdx.z % 9;
    const int ks = blockIdx.z / 9;
    const bool routed = e < NEXP;
    const int* rl = routed ? lists + e * S_LEN : nullptr;
    const int myM = routed ? counts[e] : S_LEN;
    const int m0 = blockIdx.y * 64;
    if (m0 >= myM) return;
    const long long ST = (long long)FFD * DMODEL;
    const float* Bp = routed ? wd + (long long)e * ST : wsd;
    const unsigned short* Ab = routed ? hmid : smid;
    float* Cp = routed ? (ks ? dR1 : dR0) : (ks ? dS1 : dS0);
    const int n0 = blockIdx.x * 64;
    const int kbeg = ks * (FFD / 2);

    const int tid = threadIdx.x;
    const int ar = tid >> 2, ak = (tid & 3) << 3;
    const int bn = tid & 63, bk8 = (tid >> 6) << 3;
    const int bc = ((bk8 >> 3) ^ (bn >> 3)) & 3;

    const int arow = m0 + ar;
    const bool avalid = arow < myM;
    const int arow_g = avalid ? (rl ? rl[arow] : arow) : 0;
    const unsigned short* Ap = Ab + (size_t)arow_g * FFD + ak;

    const int lane = tid & 63, wv = tid >> 6;
    const int wm = wv >> 1, wn = wv & 1;
    const int lr = lane & 15, quad = lane >> 4;

    f4v zero = {0.f, 0.f, 0.f, 0.f};
    f4v acc[2][2];
    acc[0][0] = zero; acc[0][1] = zero; acc[1][0] = zero; acc[1][1] = zero;

    for (int it = 0; it < 32; ++it) {
        const int k0 = kbeg + (it << 5);
        uint4 hv = {0, 0, 0, 0};
        if (avalid) hv = *(const uint4*)(Ap + k0);
        const float* bp = Bp + (size_t)(k0 + bk8) * DMODEL + n0 + bn;
        float f[8];
#pragma unroll
        for (int j = 0; j < 8; j++) f[j] = bp[(size_t)j * DMODEL];
        unsigned int ph[4];
#pragma unroll
        for (int j = 0; j < 4; j++)
            ph[j] = (unsigned int)f2bf(f[2 * j]) | ((unsigned int)f2bf(f[2 * j + 1]) << 16);
        __syncthreads();
        *(uint4*)&Ah[ar][ak] = hv;
        *(uint4*)&Bt[bn][bc << 3] = *(uint4*)ph;
        __syncthreads();
        const int br0 = wn * 32 + lr, br1 = wn * 32 + 16 + lr;
        const int c0 = ((quad ^ (br0 >> 3)) & 3) << 3;
        const int c1 = ((quad ^ (br1 >> 3)) & 3) << 3;
        s8v ah0 = *(const s8v*)&Ah[wm * 32 + lr][quad * 8];
        s8v ah1 = *(const s8v*)&Ah[wm * 32 + 16 + lr][quad * 8];
        s8v bh0 = *(const s8v*)&Bt[br0][c0];
        s8v bh1 = *(const s8v*)&Bt[br1][c1];
        acc[0][0] = mfma_bf16(ah0, bh0, acc[0][0]);
        acc[0][1] = mfma_bf16(ah0, bh1, acc[0][1]);
        acc[1][0] = mfma_bf16(ah1, bh0, acc[1][0]);
        acc[1][1] = mfma_bf16(ah1, bh1, acc[1][1]);
    }
#pragma unroll
    for (int t = 0; t < 2; t++)
#pragma unroll
        for (int u = 0; u < 2; u++)
#pragma unroll
            for (int r2 = 0; r2 < 4; r2++) {
                int rml = m0 + wm * 32 + t * 16 + quad * 4 + r2;
                if (rml >= myM) continue;
                int rg = rl ? rl[rml] : rml;
                int col = n0 + wn * 32 + u * 16 + lr;
                Cp[(size_t)rg * DMODEL + col] = acc[t][u][r2];
            }
}

// ---------------------------------------------------------------------------
// RoPE fused with K-split slab reduction: q = rot(qs0+qs1), k = rot(ks0+ks1)
// ---------------------------------------------------------------------------
__global__ __launch_bounds__(256) void rope2_k(const float* __restrict__ qs0,
                                               const float* __restrict__ qs1,
                                               const float* __restrict__ ks0,
                                               const float* __restrict__ ks1,
                                               float* __restrict__ qb, float* __restrict__ kb,
                                               const int* __restrict__ pos_ids) {
    int idx = blockIdx.x * 256 + threadIdx.x;
    int i = idx & 63;
    int rest = idx >> 6;
    int head = rest % (NH + NKVH);
    int s = rest / (NH + NKVH);
    if (s >= S_LEN) return;
    float pos = (float)pos_ids[s];
    float inv = (float)exp(-(double)i * (log(500000.0) / 64.0));
    float f = pos * inv;
    float c = cosf(f), sn = sinf(f);
    size_t o;
    const float* a; const float* b; float* p;
    if (head < NH) {
        o = (size_t)s * (NH * DHEAD) + head * DHEAD;
        a = qs0; b = qs1; p = qb;
    } else {
        o = (size_t)s * (NKVH * DHEAD) + (head - NH) * DHEAD;
        a = ks0; b = ks1; p = kb;
    }
    float x1 = a[o + i] + b[o + i];
    float x2 = a[o + i + 64] + b[o + i + 64];
    p[o + i] = x1 * c - x2 * sn;
    p[o + i + 64] = x2 * c + x1 * sn;
}

__global__ __launch_bounds__(256) void vadd_k(const float* __restrict__ a,
                                              const float* __restrict__ b,
                                              float* __restrict__ o) {
    int i = blockIdx.x * 256 + threadIdx.x;
    float4 x = ((const float4*)a)[i];
    float4 y = ((const float4*)b)[i];
    float4 r = {x.x + y.x, x.y + y.y, x.z + y.z, x.w + y.w};
    ((float4*)o)[i] = r;
}

// out = hbuf + dR0 + dR1 + dS0 + dS1
__global__ __launch_bounds__(256) void final_k(const float* __restrict__ hbuf,
                                               const float* __restrict__ r0,
                                               const float* __restrict__ r1,
                                               const float* __restrict__ s0,
                                               const float* __restrict__ s1,
                                               float* __restrict__ out) {
    int i = blockIdx.x * 256 + threadIdx.x;
    float4 h = ((const float4*)hbuf)[i];
    float4 a = ((const float4*)r0)[i];
    float4 b = ((const float4*)r1)[i];
    float4 c = ((const float4*)s0)[i];
    float4 d = ((const float4*)s1)[i];
    float4 r = {h.x + a.x + b.x + c.x + d.x,
                h.y + a.y + b.y + c.y + d.y,
                h.z + a.z + b.z + c.z + d.z,
                h.w + a.w + b.w + c.w + d.w};
    ((float4*)out)[i] = r;
}

// ---------------------------------------------------------------------------
// Flash-style causal attention, fp32 (unchanged from round 2)
// ---------------------------------------------------------------------------
__global__ __launch_bounds__(256) void attn_k(const float* __restrict__ qb,
                                              const float* __restrict__ kb,
                                              const float* __restrict__ vb,
                                              const int* __restrict__ amask,
                                              unsigned short* __restrict__ ohi,
                                              unsigned short* __restrict__ olo) {
    __shared__ float KV[64][133];
    __shared__ float Qs[16][133];
    __shared__ float Ps[4][4][64];
    const int qt = blockIdx.x;
    const int h = blockIdx.y;
    const int kvh = h >> 2;
    const int tid = threadIdx.x;
    const int w = tid >> 6;
    const int lane = tid & 63;
    const float qsc = 0.08838834764831845f;

    for (int i = tid; i < 16 * 128; i += 256) {
        int r = i >> 7, d = i & 127;
        Qs[r][d] = qb[(size_t)(qt * 16 + r) * (NH * DHEAD) + h * DHEAD + d] * qsc;
    }
    float m_i[4], l_i[4], o0[4], o1[4];
#pragma unroll
    for (int r = 0; r < 4; r++) { m_i[r] = -3.0e38f; l_i[r] = 0.f; o0[r] = 0.f; o1[r] = 0.f; }
    const int ntiles = ((qt * 16 + 15) >> 6) + 1;
    __syncthreads();
    for (int kt = 0; kt < ntiles; kt++) {
        for (int i = tid; i < 64 * 128; i += 256) {
            int r = i >> 7, d = i & 127;
            KV[r][d] = kb[(size_t)(kt * 64 + r) * (NKVH * DHEAD) + kvh * DHEAD + d];
        }
        __syncthreads();
        const int kg = kt * 64 + lane;
        const bool kvalid = (amask[kg] > 0);
        float sc[4] = {0.f, 0.f, 0.f, 0.f};
        for (int d = 0; d < 128; d++) {
            float kval = KV[lane][d];
#pragma unroll
            for (int r = 0; r < 4; r++) sc[r] = fmaf(Qs[w * 4 + r][d], kval, sc[r]);
        }
#pragma unroll
        for (int r = 0; r < 4; r++) {
            const int qg = qt * 16 + w * 4 + r;
            float sr = (kvalid && kg <= qg) ? sc[r] : -1.0e30f;
            float mt = sr;
            for (int off = 32; off > 0; off >>= 1) mt = fmaxf(mt, __shfl_xor(mt, off));
            float mn = fmaxf(m_i[r], mt);
            float p = expf(sr - mn);
            float alpha = expf(m_i[r] - mn);
            float psum = p;
            for (int off = 32; off > 0; off >>= 1) psum += __shfl_xor(psum, off);
            l_i[r] = l_i[r] * alpha + psum;
            m_i[r] = mn;
            o0[r] *= alpha; o1[r] *= alpha;
            Ps[w][r][lane] = p;
        }
        __syncthreads();
        for (int i = tid; i < 64 * 128; i += 256) {
            int r = i >> 7, d = i & 127;
            KV[r][d] = vb[(size_t)(kt * 64 + r) * (NKVH * DHEAD) + kvh * DHEAD + d];
        }
        __syncthreads();
#pragma unroll 4
        for (int j = 0; j < 64; j++) {
            float v0 = KV[j][lane];
            float v1 = KV[j][lane + 64];
#pragma unroll
            for (int r = 0; r < 4; r++) {
                float p = Ps[w][r][j];
                o0[r] = fmaf(p, v0, o0[r]);
                o1[r] = fmaf(p, v1, o1[r]);
            }
        }
        __syncthreads();
    }
#pragma unroll
    for (int r = 0; r < 4; r++) {
        const int qg = qt * 16 + w * 4 + r;
        float linv = 1.0f / l_i[r];
        float a0 = o0[r] * linv, a1 = o1[r] * linv;
        size_t base = (size_t)qg * (NH * DHEAD) + h * DHEAD;
        unsigned short h0 = f2bf(a0), h1 = f2bf(a1);
        ohi[base + lane] = h0;
        ohi[base + lane + 64] = h1;
        olo[base + lane] = f2bf(a0 - bf2f(h0));
        olo[base + lane + 64] = f2bf(a1 - bf2f(h1));
    }
}

// ---------------------------------------------------------------------------
__global__ __launch_bounds__(256) void router_k(const float* __restrict__ x2f,
                                                const float* __restrict__ rw,
                                                float* __restrict__ logits) {
    int t = blockIdx.x;
    int e = threadIdx.x >> 5;
    int j = threadIdx.x & 31;
    const float* xr = x2f + (size_t)t * DMODEL;
    float p = 0.f;
    for (int k = j; k < DMODEL; k += 32) p = fmaf(xr[k], rw[(size_t)k * NEXP + e], p);
    for (int off = 16; off > 0; off >>= 1) p += __shfl_xor(p, off);
    if (j == 0) logits[t * NEXP + e] = p;
}

__global__ __launch_bounds__(512) void route_build_k(const float* __restrict__ logits,
                                                     float* __restrict__ tscore,
                                                     int* __restrict__ counts,
                                                     int* __restrict__ lists) {
    int t = threadIdx.x;
    const float* lg = logits + t * NEXP;
    int best = 0;
    float bv = lg[0];
#pragma unroll
    for (int e = 1; e < NEXP; e++) { float v = lg[e]; if (v > bv) { bv = v; best = e; } }
    tscore[t] = 1.0f / (1.0f + expf(-bv));
    int pos = atomicAdd(&counts[best], 1);
    lists[best * S_LEN + pos] = t;
}

// ---------------------------------------------------------------------------
extern "C" void kernel_launch(void* const* d_in, const int* in_sizes, int n_in,
                              void* d_out, int out_size, void* d_ws, size_t ws_size,
                              hipStream_t stream) {
    const float* hidden = (const float*)d_in[0];
    const int* amask = (const int*)d_in[1];
    const int* posid = (const int*)d_in[2];
    const float* anw = (const float*)d_in[3];
    const float* wq = (const float*)d_in[4];
    const float* wk = (const float*)d_in[5];
    const float* wvv = (const float*)d_in[6];
    const float* wo = (const float*)d_in[7];
    const float* fnw = (const float*)d_in[8];
    const float* rw = (const float*)d_in[9];
    const float* wg = (const float*)d_in[10];
    const float* wu = (const float*)d_in[11];
    const float* wd = (const float*)d_in[12];
    const float* wsg = (const float*)d_in[13];
    const float* wsu = (const float*)d_in[14];
    const float* wsd = (const float*)d_in[15];
    float* out = (float*)d_out;

    char* ws = (char*)d_ws;
    const size_t MB = 1024 * 1024;
    // region 0 (0..4MB): x1h,x1l  -> later dR0
    unsigned short* x1h = (unsigned short*)(ws + 0);
    unsigned short* x1l = (unsigned short*)(ws + 2 * MB);
    float* dR0 = (float*)(ws + 0);
    // region 1 (4..8MB): qs0 -> hs0 -> dS0
    float* qs0 = (float*)(ws + 4 * MB);
    float* hs0 = (float*)(ws + 4 * MB);
    float* dS0 = (float*)(ws + 4 * MB);
    // region 2 (8..12MB): qs1 -> hs1 -> dS1
    float* qs1 = (float*)(ws + 8 * MB);
    float* hs1 = (float*)(ws + 8 * MB);
    float* dS1 = (float*)(ws + 8 * MB);
    // region 3 (12..14MB): ks0,ks1
    float* ks0 = (float*)(ws + 12 * MB);
    float* ks1 = (float*)(ws + 13 * MB);
    // region 4 (14..16MB): vs0,vs1
    float* vs0 = (float*)(ws + 14 * MB);
    float* vs1 = (float*)(ws + 15 * MB);
    // region 5 (16..22MB): qb,kb,vb
    float* qb = (float*)(ws + 16 * MB);
    float* kb = (float*)(ws + 20 * MB);
    float* vb = (float*)(ws + 21 * MB);
    // region 6 (22..26MB): ath,atl -> later dR1
    unsigned short* ath = (unsigned short*)(ws + 22 * MB);
    unsigned short* atl = (unsigned short*)(ws + 24 * MB);
    float* dR1 = (float*)(ws + 22 * MB);
    // persistent: hbuf, x2f, x2b, hmid, smid, router stuff
    float* hbuf = (float*)(ws + 26 * MB);
    float* x2f = (float*)(ws + 30 * MB);
    unsigned short* x2b = (unsigned short*)(ws + 34 * MB);
    unsigned short* hmid = (unsigned short*)(ws + 36 * MB);
    unsigned short* smid = (unsigned short*)(ws + 38 * MB);
    float* logits = (float*)(ws + 40 * MB);
    float* tscore = (float*)(ws + 40 * MB + 16384);
    int* counts = (int*)(ws + 40 * MB + 20480);
    int* lists = (int*)(ws + 40 * MB + 24576);

    hipMemsetAsync(counts, 0, NEXP * 4, stream);

    // ---- attention block ----
    rms_pair_k<<<S_LEN, 256, 0, stream>>>(hidden, anw, x1h, x1l);
    {
        S3Args a;
        a.Ahi = x1h; a.Alo = x1l;
        a.B0 = wq; a.B1 = wk; a.B2 = wvv;
        a.C00 = qs0; a.C01 = qs1; a.C10 = ks0; a.C11 = ks1; a.C20 = vs0; a.C21 = vs1;
        a.N0 = 2048; a.N1 = 512; a.N2 = 512;
        a.x1 = 32; a.x2 = 40;
        gemm_split3_k<<<dim3(48, 8, 2), 256, 0, stream>>>(a);
    }
    rope2_k<<<2560, 256, 0, stream>>>(qs0, qs1, ks0, ks1, qb, kb, posid);
    vadd_k<<<(S_LEN * NKVH * DHEAD / 4) / 256, 256, 0, stream>>>(vs0, vs1, vb);
    attn_k<<<dim3(32, NH), 256, 0, stream>>>(qb, kb, vb, amask, ath, atl);
    {
        S3Args a;
        a.Ahi = ath; a.Alo = atl;
        a.B0 = wo; a.B1 = nullptr; a.B2 = nullptr;
        a.C00 = hs0; a.C01 = hs1; a.C10 = nullptr; a.C11 = nullptr; a.C20 = nullptr; a.C21 = nullptr;
        a.N0 = 2048; a.N1 = 0; a.N2 = 0;
        a.x1 = 32; a.x2 = 40;
        gemm_split3_k<<<dim3(32, 8, 2), 256, 0, stream>>>(a);
    }
    rms_dual2_k<<<S_LEN, 256, 0, stream>>>(hidden, hs0, hs1, fnw, hbuf, x2f, x2b);

    // ---- MoE block ----
    router_k<<<S_LEN, 256, 0, stream>>>(x2f, rw, logits);
    route_build_k<<<1, 512, 0, stream>>>(logits, tscore, counts, lists);
    gemm_gu_k<<<dim3(32, 8, 9), 256, 0, stream>>>(x2b, wg, wu, wsg, wsu, tscore,
                                                  lists, counts, hmid, smid);
    gemm_dn_k<<<dim3(32, 8, 18), 256, 0, stream>>>(hmid, smid, wd, wsd, lists, counts,
                                                   dR0, dR1, dS0, dS1);
    final_k<<<(S_LEN * DMODEL / 4) / 256, 256, 0, stream>>>(hbuf, dR0, dR1, dS0, dS1, out);
}